// Round 12
// baseline (240.313 us; speedup 1.0000x reference)
//
#include <hip/hip_runtime.h>

// Problem constants (match reference setup_inputs)
constexpr int CN0 = 1000000;   // x rows
constexpr int CN1 = 300000;    // stem conv output rows
constexpr int CN2 = 80000;     // pooled rows
constexpr int CN3 = 30000;     // downsampled rows
constexpr float BN_EPS = 1e-5f;

typedef __attribute__((ext_vector_type(8))) short bf16x8;
typedef __attribute__((ext_vector_type(4))) float f32x4;

union FragU { uint4 u; bf16x8 b; };

__device__ __forceinline__ float2 bn_ab(float s, float q, float invn, float gamma, float beta) {
  float m = s * invn;
  float v = fmaf(q, invn, -m * m);
  float rstd = rsqrtf(v + BN_EPS);
  float a = gamma * rstd;
  float b = beta - m * a;
  return make_float2(a, b);
}

// round-to-nearest-even fp32 -> bf16
__device__ __forceinline__ unsigned short f2bf(float f) {
  unsigned u = __float_as_uint(f);
  u += 0x7FFFu + ((u >> 16) & 1u);
  return (unsigned short)(u >> 16);
}

// LDS-only barrier: waits ds ops, does NOT drain vmcnt -> prefetched global
// loads stay in flight across the barrier.
__device__ __forceinline__ void sync_lds() {
  asm volatile("s_waitcnt lgkmcnt(0)" ::: "memory");
  __builtin_amdgcn_s_barrier();
  asm volatile("" ::: "memory");
}

// ---------------------------------------------------------------------------
// Prep: x (f32 [1M][4]) -> xbf (bf16 [1M][4])
// ---------------------------------------------------------------------------
__global__ __launch_bounds__(256) void k_prep_x(
    const float* __restrict__ x, unsigned int* __restrict__ xbf) {
  int i = blockIdx.x * 256 + threadIdx.x;
  if (i >= CN0) return;
  float4 v = *(const float4*)(x + i * 4);
  uint2 p;
  p.x = (unsigned)f2bf(v.x) | ((unsigned)f2bf(v.y) << 16);
  p.y = (unsigned)f2bf(v.z) | ((unsigned)f2bf(v.w) << 16);
  *(uint2*)(xbf + i * 2) = p;
}

// ---------------------------------------------------------------------------
// Prep: W_stem [27][4][64] f32 -> per-lane MFMA B fragments:
// Wf[((ks*4+nf)*64 + lane)*8 + e] = W[k][d], k=ks*32+(lane>>4)*8+e (pad>=108),
// d = nf*16+(lane&15).
// ---------------------------------------------------------------------------
__global__ __launch_bounds__(256) void k_prep_stem(
    const float* __restrict__ W, unsigned short* __restrict__ Wt) {
  int f = blockIdx.x * 256 + threadIdx.x;  // 8192
  if (f >= 8192) return;
  int e = f & 7, lane = (f >> 3) & 63, nf = (f >> 9) & 3, ks = f >> 11;
  int k = ks * 32 + (lane >> 4) * 8 + e;
  int d = nf * 16 + (lane & 15);
  Wt[f] = (k < 108) ? f2bf(W[k * 64 + d]) : (unsigned short)0;
}

// ---------------------------------------------------------------------------
// Prep: dual weights [W1|Wd] -> per-lane fragment layout
// Wf[tap][ks1][nfg(0..7)][lane][e]: cin=ks1*32+(lane>>4)*8+e, d=nfg*16+(lane&15)
// ---------------------------------------------------------------------------
__global__ __launch_bounds__(256) void k_prep_dual(
    const float* __restrict__ W1, const float* __restrict__ Wd,
    unsigned short* __restrict__ Wf) {
  int f = blockIdx.x * 256 + threadIdx.x;  // 27*8192 = 221184
  if (f >= 27 * 8192) return;
  int tap = f >> 13, r = f & 8191;
  int ks1 = (r >> 12) & 1, nfg = (r >> 9) & 7, lane = (r >> 3) & 63, e = r & 7;
  int cin = ks1 * 32 + (lane >> 4) * 8 + e;
  int d = nfg * 16 + (lane & 15);
  float v = (d < 64) ? W1[(tap * 64 + cin) * 64 + d]
                     : Wd[(tap * 64 + cin) * 64 + (d - 64)];
  Wf[f] = f2bf(v);
}

__global__ __launch_bounds__(256) void k_prep_res(
    const float* __restrict__ W2, unsigned short* __restrict__ Wf) {
  int f = blockIdx.x * 256 + threadIdx.x;  // 27*4096 = 110592
  if (f >= 27 * 4096) return;
  int tap = f >> 12, r = f & 4095;
  int ks1 = (r >> 11) & 1, nfg = (r >> 9) & 3, lane = (r >> 3) & 63, e = r & 7;
  int cin = ks1 * 32 + (lane >> 4) * 8 + e;
  int d = nfg * 16 + (lane & 15);
  Wf[f] = f2bf(W2[(tap * 64 + cin) * 64 + d]);
}

// ---------------------------------------------------------------------------
// Stem conv via MFMA, register-direct gather, T=4 tiles/block, 2-DEEP gather
// pipeline: 3 frag/idx buffers; gather(t+2) issued at tile t rides across two
// compute+epilogue windows. FP order per tile unchanged (r6 numerics).
// ---------------------------------------------------------------------------
__global__ __launch_bounds__(256) void k_stem_mfma(
    const unsigned short* __restrict__ xbf, const int* __restrict__ neigh,
    const unsigned short* __restrict__ Wf, unsigned short* __restrict__ y1,
    float* __restrict__ stats) {
  constexpr int T = 4;  // tiles (of 64 nodes) per block; 1172 blocks
  __shared__ __align__(16) uint4 Bb[1024];  // 16 KB: B fragments, staged once
  const int tid = threadIdx.x;
  const int lane = tid & 63;
  const int wv = tid >> 6;
  const int l15 = lane & 15, lq = lane >> 4;
  const int g0 = blockIdx.x * T;

  // Stage B fragments (linear copy, conflict-free reads later)
  {
    const uint4* Wsrc = (const uint4*)Wf;
#pragma unroll
    for (int j = 0; j < 4; ++j) Bb[tid + j * 256] = Wsrc[tid + j * 256];
  }
  __syncthreads();  // nothing valuable in flight yet

  int idx0[8], idx1[8], idx2[8];
  FragU fA[4], fB[4], fC[4];

#define LDIDX(g, dst)                                                   \
  {                                                                     \
    int node_ = (g)*64 + wv * 16 + l15;                                 \
    bool rowok_ = node_ < CN1;                                          \
    const int* nb_ = neigh + node_ * 27;                                \
    _Pragma("unroll") for (int ks_ = 0; ks_ < 4; ++ks_) {               \
      int tap0_ = ks_ * 8 + lq * 2;                                     \
      dst[ks_ * 2] = (rowok_ && tap0_ < 27) ? nb_[tap0_] : -1;          \
      dst[ks_ * 2 + 1] = (rowok_ && tap0_ + 1 < 27) ? nb_[tap0_ + 1] : -1; \
    }                                                                   \
  }

#define GATHER(idx, frag)                                               \
  {                                                                     \
    _Pragma("unroll") for (int ks_ = 0; ks_ < 4; ++ks_) {               \
      uint2 v0_ = {0u, 0u}, v1_ = {0u, 0u};                             \
      if (idx[ks_ * 2] >= 0)                                            \
        v0_ = *(const uint2*)(xbf + idx[ks_ * 2] * 4);                  \
      if (idx[ks_ * 2 + 1] >= 0)                                        \
        v1_ = *(const uint2*)(xbf + idx[ks_ * 2 + 1] * 4);              \
      frag[ks_].u.x = v0_.x; frag[ks_].u.y = v0_.y;                     \
      frag[ks_].u.z = v1_.x; frag[ks_].u.w = v1_.y;                     \
    }                                                                   \
  }

  // prologue: idx tiles 0..2, gathers tiles 0..1 (2-deep fill)
  LDIDX(0 + g0, idx0);
  LDIDX(1 + g0, idx1);
  LDIDX(2 + g0, idx2);
  GATHER(idx0, fA);
  GATHER(idx1, fB);

  float sacc[4] = {0.f, 0.f, 0.f, 0.f};
  float qacc[4] = {0.f, 0.f, 0.f, 0.f};

#pragma unroll
  for (int t = 0; t < T; ++t) {
    FragU* cur = (t % 3 == 0) ? fA : (t % 3 == 1) ? fB : fC;
    FragU* g2 = ((t + 2) % 3 == 0) ? fA : ((t + 2) % 3 == 1) ? fB : fC;
    int* ig2 = ((t + 2) % 3 == 0) ? idx0 : ((t + 2) % 3 == 1) ? idx1 : idx2;
    int* il3 = ((t + 3) % 3 == 0) ? idx0 : ((t + 3) % 3 == 1) ? idx1 : idx2;
    // issue gathers for tile t+2 and idx for tile t+3 (ride 2 windows)
    if (t + 2 < T) GATHER(ig2, g2);
    if (t + 3 < T) LDIDX(g0 + t + 3, il3);

    // compute: 4 K-substeps x 4 col-fragments; B from LDS
    f32x4 acc[4] = {};
#pragma unroll
    for (int ks = 0; ks < 4; ++ks) {
#pragma unroll
      for (int nf = 0; nf < 4; ++nf) {
        bf16x8 b = *(const bf16x8*)&Bb[(ks * 4 + nf) * 64 + lane];
        acc[nf] = __builtin_amdgcn_mfma_f32_16x16x32_bf16(cur[ks].b, b,
                                                          acc[nf], 0, 0, 0);
      }
    }

    // epilogue: store + register stats. C/D: col=lane&15, row=(lane>>4)*4+r
    int n0 = (g0 + t) * 64 + wv * 16;
#pragma unroll
    for (int nf = 0; nf < 4; ++nf) {
      int c = nf * 16 + l15;
#pragma unroll
      for (int r = 0; r < 4; ++r) {
        int row = n0 + lq * 4 + r;
        float v = acc[nf][r];
        if (row < CN1) y1[row * 64 + c] = f2bf(v);
        sacc[nf] += v;
        qacc[nf] = fmaf(v, v, qacc[nf]);
      }
    }
  }
#undef LDIDX
#undef GATHER

  // cross-wave stats reduction (reuse Bb as scratch), one atomic set/block
  __syncthreads();
  float* S = (float*)Bb;  // [2][4 waves][64 cols]
#pragma unroll
  for (int nf = 0; nf < 4; ++nf) {
    float s = sacc[nf], q = qacc[nf];
    s += __shfl_xor(s, 16); s += __shfl_xor(s, 32);
    q += __shfl_xor(q, 16); q += __shfl_xor(q, 32);
    if (lane < 16) {
      S[wv * 64 + nf * 16 + lane] = s;
      S[256 + wv * 64 + nf * 16 + lane] = q;
    }
  }
  __syncthreads();
  if (tid < 64) {
    float s = S[tid] + S[64 + tid] + S[128 + tid] + S[192 + tid];
    float q = S[256 + tid] + S[320 + tid] + S[384 + tid] + S[448 + tid];
    atomicAdd(&stats[tid], s);
    atomicAdd(&stats[64 + tid], q);
  }
}

// ---------------------------------------------------------------------------
// Pool: h2[n][c] = relu(max_j BN(y1[child[n][j]][c])) on packed bf16 y1.
// ---------------------------------------------------------------------------
__global__ __launch_bounds__(256) void k_pool(
    const unsigned int* __restrict__ y1, const int* __restrict__ child,
    const float* __restrict__ stats, const float* __restrict__ gamma,
    const float* __restrict__ beta, unsigned int* __restrict__ h2) {
  const int tid = threadIdx.x;
  const int wd = tid & 31;
  const int n = blockIdx.x * 8 + (tid >> 5);
  const int c0 = wd * 2, c1 = c0 + 1;
  const int* crow = child + n * 8;
  int ch[8];
#pragma unroll
  for (int j = 0; j < 8; ++j) ch[j] = crow[j];
  unsigned vv[8];
#pragma unroll
  for (int j = 0; j < 8; ++j) vv[j] = y1[ch[j] * 32 + wd];

  float2 ab0 = bn_ab(stats[c0], stats[64 + c0], 1.0f / CN1, gamma[c0], beta[c0]);
  float2 ab1 = bn_ab(stats[c1], stats[64 + c1], 1.0f / CN1, gamma[c1], beta[c1]);
  float mx0 = -INFINITY, mn0 = INFINITY, mx1 = -INFINITY, mn1 = INFINITY;
#pragma unroll
  for (int j = 0; j < 8; ++j) {
    float v0 = __uint_as_float(vv[j] << 16);
    float v1 = __uint_as_float(vv[j] & 0xFFFF0000u);
    mx0 = fmaxf(mx0, v0); mn0 = fminf(mn0, v0);
    mx1 = fmaxf(mx1, v1); mn1 = fminf(mn1, v1);
  }
  float t0 = (ab0.x > 0.f) ? fmaf(ab0.x, mx0, ab0.y) : fmaf(ab0.x, mn0, ab0.y);
  float t1 = (ab1.x > 0.f) ? fmaf(ab1.x, mx1, ab1.y) : fmaf(ab1.x, mn1, ab1.y);
  unsigned o = (unsigned)f2bf(fmaxf(t0, 0.f)) |
               ((unsigned)f2bf(fmaxf(t1, 0.f)) << 16);
  h2[n * 32 + wd] = o;
}

// ---------------------------------------------------------------------------
// MFMA gathered conv, barrier-free / array-free, 32-node waves, 2-DEEP B
// prefetch: qa/qb/qc rotation, B for tap k+2 issued at tap k (~2 taps of
// MFMA cover L2 latency). A gathers 3 taps deep as before. All pipeline
// state = named scalars. FP order identical to r11.
// ---------------------------------------------------------------------------
template <int OUTC>
__global__ __launch_bounds__(OUTC * 2) void k_mconv(
    const unsigned short* __restrict__ src, const int* __restrict__ neigh,
    const unsigned short* __restrict__ Wf, float* __restrict__ out,
    float* __restrict__ stats, int M) {
  constexpr int CG = OUTC / 64;      // col groups (2 or 1)
  constexpr int THREADS = OUTC * 2;  // 256 or 128
  constexpr int PT = CG * 512;       // uint4 per tap
  constexpr int K1 = 4 * CG;         // ks1=1 fragment offset (frags)
  __shared__ int nlds[64 * 27];

  const int tid = threadIdx.x;
  const int lane = tid & 63;
  const int w = tid >> 6;
  const int ng = w & 1, cg = w >> 1;   // cg==0 when OUTC==64
  const int l15 = lane & 15, lq = lane >> 4;
  const uint4* WfU = (const uint4*)Wf;
  const int cg4 = cg * 4;
  const int offA = (ng * 32 + l15) * 27;  // LDS idx offsets (literal +k reads)
  const int offB = offA + 16 * 27;

  // stage all 64 nodes' neighbor indices (coalesced)
  for (int e = tid; e < 64 * 27; e += THREADS) {
    int row = blockIdx.x * 64 + e / 27;
    nlds[e] = (row < M) ? neigh[row * 27 + e % 27] : -1;
  }

  FragU x0l, x0h, x1l, x1h, x2l, x2h;  // group A frags, 3-slot rotation
  FragU y0l, y0h, y1l, y1h, y2l, y2h;  // group B frags
  FragU qa0, qa1, qa2, qa3, qa4, qa5, qa6, qa7;  // B 3-buf
  FragU qb0, qb1, qb2, qb3, qb4, qb5, qb6, qb7;
  FragU qc0, qc1, qc2, qc3, qc4, qc5, qc6, qc7;
  f32x4 ca0 = {0.f, 0.f, 0.f, 0.f}, ca1 = {0.f, 0.f, 0.f, 0.f};
  f32x4 ca2 = {0.f, 0.f, 0.f, 0.f}, ca3 = {0.f, 0.f, 0.f, 0.f};
  f32x4 cb0 = {0.f, 0.f, 0.f, 0.f}, cb1 = {0.f, 0.f, 0.f, 0.f};
  f32x4 cb2 = {0.f, 0.f, 0.f, 0.f}, cb3 = {0.f, 0.f, 0.f, 0.f};

#define LDB(QP, k)                                                         \
  {                                                                        \
    const uint4* bp_ = WfU + ((k)*PT + cg4 * 64 + lane);                   \
    (QP##0).u = bp_[0];                                                    \
    (QP##1).u = bp_[64];                                                   \
    (QP##2).u = bp_[128];                                                  \
    (QP##3).u = bp_[192];                                                  \
    (QP##4).u = bp_[K1 * 64];                                              \
    (QP##5).u = bp_[K1 * 64 + 64];                                         \
    (QP##6).u = bp_[K1 * 64 + 128];                                        \
    (QP##7).u = bp_[K1 * 64 + 192];                                        \
  }

#define GATH2(AL, AH, ix)                                                  \
  {                                                                        \
    int ix_ = (ix);                                                        \
    if (ix_ >= 0) {                                                        \
      const char* bp_ = (const char*)src + (size_t)ix_ * 128 + lq * 16;    \
      AL.u = *(const uint4*)bp_;                                           \
      AH.u = *(const uint4*)(bp_ + 64);                                    \
    } else {                                                               \
      AL.u = uint4{0u, 0u, 0u, 0u};                                        \
      AH.u = uint4{0u, 0u, 0u, 0u};                                        \
    }                                                                      \
  }

// per-acc order: (l, Qlow) then (h, Qhigh) — identical numerics to r11;
// chains interleaved c0..c3 so dependent MFMAs are 4 apart.
#define MMG(AL, AH, C0, C1, C2, C3, QP)                                       \
  C0 = __builtin_amdgcn_mfma_f32_16x16x32_bf16((AL).b, (QP##0).b, C0, 0, 0, 0); \
  C1 = __builtin_amdgcn_mfma_f32_16x16x32_bf16((AL).b, (QP##1).b, C1, 0, 0, 0); \
  C2 = __builtin_amdgcn_mfma_f32_16x16x32_bf16((AL).b, (QP##2).b, C2, 0, 0, 0); \
  C3 = __builtin_amdgcn_mfma_f32_16x16x32_bf16((AL).b, (QP##3).b, C3, 0, 0, 0); \
  C0 = __builtin_amdgcn_mfma_f32_16x16x32_bf16((AH).b, (QP##4).b, C0, 0, 0, 0); \
  C1 = __builtin_amdgcn_mfma_f32_16x16x32_bf16((AH).b, (QP##5).b, C1, 0, 0, 0); \
  C2 = __builtin_amdgcn_mfma_f32_16x16x32_bf16((AH).b, (QP##6).b, C2, 0, 0, 0); \
  C3 = __builtin_amdgcn_mfma_f32_16x16x32_bf16((AH).b, (QP##7).b, C3, 0, 0, 0);

// TAP(k): prefetch B tap k+2 -> QN2; MFMA tap k (both groups, shared QP);
// gather tap k+3 into freed slots (idx read inline from LDS, literal k+3).
#define TAP(k, XL, XH, YL, YH, QP, QN2)                \
  {                                                    \
    if ((k) + 2 < 27) LDB(QN2, (k) + 2)                \
    MMG(XL, XH, ca0, ca1, ca2, ca3, QP)                \
    MMG(YL, YH, cb0, cb1, cb2, cb3, QP)                \
    if ((k) + 3 < 27) {                                \
      GATH2(XL, XH, nlds[offA + (k) + 3])              \
      GATH2(YL, YH, nlds[offB + (k) + 3])              \
    }                                                  \
  }

  // B taps 0,1 issued before the barrier (ride across it)
  LDB(qa, 0)
  LDB(qb, 1)
  sync_lds();  // nlds visible

  // prologue gathers: taps 0..2, both groups (12 uint4 in flight)
  GATH2(x0l, x0h, nlds[offA + 0])
  GATH2(y0l, y0h, nlds[offB + 0])
  GATH2(x1l, x1h, nlds[offA + 1])
  GATH2(y1l, y1h, nlds[offB + 1])
  GATH2(x2l, x2h, nlds[offA + 2])
  GATH2(y2l, y2h, nlds[offB + 2])

  TAP(0, x0l, x0h, y0l, y0h, qa, qc)
  TAP(1, x1l, x1h, y1l, y1h, qb, qa)
  TAP(2, x2l, x2h, y2l, y2h, qc, qb)
  TAP(3, x0l, x0h, y0l, y0h, qa, qc)
  TAP(4, x1l, x1h, y1l, y1h, qb, qa)
  TAP(5, x2l, x2h, y2l, y2h, qc, qb)
  TAP(6, x0l, x0h, y0l, y0h, qa, qc)
  TAP(7, x1l, x1h, y1l, y1h, qb, qa)
  TAP(8, x2l, x2h, y2l, y2h, qc, qb)
  TAP(9, x0l, x0h, y0l, y0h, qa, qc)
  TAP(10, x1l, x1h, y1l, y1h, qb, qa)
  TAP(11, x2l, x2h, y2l, y2h, qc, qb)
  TAP(12, x0l, x0h, y0l, y0h, qa, qc)
  TAP(13, x1l, x1h, y1l, y1h, qb, qa)
  TAP(14, x2l, x2h, y2l, y2h, qc, qb)
  TAP(15, x0l, x0h, y0l, y0h, qa, qc)
  TAP(16, x1l, x1h, y1l, y1h, qb, qa)
  TAP(17, x2l, x2h, y2l, y2h, qc, qb)
  TAP(18, x0l, x0h, y0l, y0h, qa, qc)
  TAP(19, x1l, x1h, y1l, y1h, qb, qa)
  TAP(20, x2l, x2h, y2l, y2h, qc, qb)
  TAP(21, x0l, x0h, y0l, y0h, qa, qc)
  TAP(22, x1l, x1h, y1l, y1h, qb, qa)
  TAP(23, x2l, x2h, y2l, y2h, qc, qb)
  TAP(24, x0l, x0h, y0l, y0h, qa, qc)
  TAP(25, x1l, x1h, y1l, y1h, qb, qa)
  TAP(26, x2l, x2h, y2l, y2h, qc, qb)
#undef TAP
#undef MMG
#undef GATH2
#undef LDB

  // store (C/D: col=lane&15, row=(lane>>4)*4+r); group x rows, then +16
  const int rbA = blockIdx.x * 64 + ng * 32 + lq * 4;
#pragma unroll
  for (int nf = 0; nf < 4; ++nf) {
    f32x4 a = (nf == 0) ? ca0 : (nf == 1) ? ca1 : (nf == 2) ? ca2 : ca3;
    f32x4 b = (nf == 0) ? cb0 : (nf == 1) ? cb1 : (nf == 2) ? cb2 : cb3;
    int c = cg * 64 + nf * 16 + l15;
#pragma unroll
    for (int r = 0; r < 4; ++r) {
      int rowA = rbA + r, rowB = rbA + 16 + r;
      if (rowA < M) out[rowA * OUTC + c] = a[r];
      if (rowB < M) out[rowB * OUTC + c] = b[r];
    }
  }

  // stats (invalid rows contributed zeros); sum both groups
#pragma unroll
  for (int nf = 0; nf < 4; ++nf) {
    f32x4 a = (nf == 0) ? ca0 : (nf == 1) ? ca1 : (nf == 2) ? ca2 : ca3;
    f32x4 b = (nf == 0) ? cb0 : (nf == 1) ? cb1 : (nf == 2) ? cb2 : cb3;
    float s = 0.f, q = 0.f;
#pragma unroll
    for (int r = 0; r < 4; ++r) {
      s += a[r] + b[r];
      q += a[r] * a[r] + b[r] * b[r];
    }
    s += __shfl_xor(s, 16); s += __shfl_xor(s, 32);
    q += __shfl_xor(q, 16); q += __shfl_xor(q, 32);
    if (lane < 16) {
      int c = cg * 64 + nf * 16 + lane;
      atomicAdd(&stats[c], s);
      atomicAdd(&stats[OUTC + c], q);
    }
  }
}

// ---------------------------------------------------------------------------
// BN+ReLU on y2d channels 0..63 -> out1 (bf16)
// ---------------------------------------------------------------------------
__global__ __launch_bounds__(256) void k_bnrelu(
    const float* __restrict__ y2d, const float* __restrict__ stats,
    const float* __restrict__ gamma, const float* __restrict__ beta,
    unsigned short* __restrict__ out1) {
  int e = blockIdx.x * 256 + threadIdx.x;
  int i = e >> 6, c = e & 63;
  float2 ab = bn_ab(stats[c], stats[128 + c], 1.0f / CN3, gamma[c], beta[c]);
  out1[e] = f2bf(fmaxf(fmaf(ab.x, y2d[i * 128 + c], ab.y), 0.f));
}

// ---------------------------------------------------------------------------
// Final: relu(BN2(y3) + BNd(y2d[:,64:128]))
// ---------------------------------------------------------------------------
__global__ __launch_bounds__(256) void k_final(
    const float* __restrict__ y3, const float* __restrict__ y2d,
    const float* __restrict__ stats2, const float* __restrict__ stats1d,
    const float* __restrict__ g2, const float* __restrict__ b2,
    const float* __restrict__ gd, const float* __restrict__ bd,
    float* __restrict__ dout) {
  int e = blockIdx.x * 256 + threadIdx.x;
  int i = e >> 6, c = e & 63;
  float2 ab2 = bn_ab(stats2[c], stats2[64 + c], 1.0f / CN3, g2[c], b2[c]);
  float2 abd =
      bn_ab(stats1d[64 + c], stats1d[192 + c], 1.0f / CN3, gd[c], bd[c]);
  float o = fmaf(ab2.x, y3[e], ab2.y) + fmaf(abd.x, y2d[i * 128 + 64 + c], abd.y);
  dout[e] = fmaxf(o, 0.f);
}

// ---------------------------------------------------------------------------
extern "C" void kernel_launch(void* const* d_in, const int* in_sizes, int n_in,
                              void* d_out, int out_size, void* d_ws,
                              size_t ws_size, hipStream_t stream) {
  const float* x = (const float*)d_in[0];
  const int* neigh_stem = (const int*)d_in[1];
  const int* pool_child = (const int*)d_in[2];
  const int* neigh_ds = (const int*)d_in[3];
  const int* neigh_res = (const int*)d_in[4];
  const float* W_stem = (const float*)d_in[5];
  const float* g_stem = (const float*)d_in[6];
  const float* b_stem = (const float*)d_in[7];
  const float* W1 = (const float*)d_in[8];
  const float* g1 = (const float*)d_in[9];
  const float* b1 = (const float*)d_in[10];
  const float* W2 = (const float*)d_in[11];
  const float* g2 = (const float*)d_in[12];
  const float* b2 = (const float*)d_in[13];
  const float* Wd = (const float*)d_in[14];
  const float* gd = (const float*)d_in[15];
  const float* bd = (const float*)d_in[16];
  float* out = (float*)d_out;
  float* ws = (float*)d_ws;

  // Workspace layout (float units):
  unsigned short* y1bf = (unsigned short*)ws;              // N1*64 bf16 (9.6M f)
  float* y2d = ws;                                         // N3*128 f32 (reuse)
  unsigned short* out1bf = (unsigned short*)(ws + 3840000);// N3*64 bf16
  float* y3 = ws + 4800000;                                // N3*64 f32
  unsigned short* h2bf = (unsigned short*)(ws + 9600000);  // N2*64 bf16 (2.56M f)
  unsigned int* xbf = (unsigned int*)(ws + 12160000);      // N0*4 bf16 (2M f)
  unsigned short* Wst = (unsigned short*)(ws + 14160000);  // 8192 bf16
  unsigned short* Wdual = (unsigned short*)(ws + 14164096);// 221184 bf16
  unsigned short* Wres = (unsigned short*)(ws + 14274688); // 110592 bf16
  float* stats = ws + 14329984;                            // 512 f32
  float* stats_stem = stats;                               // [128]
  float* stats_1d = stats + 128;                           // [256]
  float* stats_2 = stats + 384;                            // [128]

  hipMemsetAsync(stats, 0, 512 * sizeof(float), stream);

  k_prep_x<<<(CN0 + 255) / 256, 256, 0, stream>>>(x, xbf);
  k_prep_stem<<<(8192 + 255) / 256, 256, 0, stream>>>(W_stem, Wst);
  k_prep_dual<<<(27 * 8192 + 255) / 256, 256, 0, stream>>>(W1, Wd, Wdual);
  k_prep_res<<<(27 * 4096 + 255) / 256, 256, 0, stream>>>(W2, Wres);

  // 4688 tiles of 64 nodes = 4 tiles x 1172 blocks
  k_stem_mfma<<<1172, 256, 0, stream>>>(
      (const unsigned short*)xbf, neigh_stem, Wst, y1bf, stats_stem);
  k_pool<<<CN2 / 8, 256, 0, stream>>>((const unsigned int*)y1bf, pool_child,
                                      stats_stem, g_stem, b_stem,
                                      (unsigned int*)h2bf);
  // 469 blocks of 64 nodes
  k_mconv<128><<<(CN3 + 63) / 64, 256, 0, stream>>>(h2bf, neigh_ds, Wdual,
                                                    y2d, stats_1d, CN3);
  k_bnrelu<<<CN3 * 64 / 256, 256, 0, stream>>>(y2d, stats_1d, g1, b1, out1bf);
  k_mconv<64><<<(CN3 + 63) / 64, 128, 0, stream>>>(out1bf, neigh_res, Wres,
                                                   y3, stats_2, CN3);
  k_final<<<CN3 * 64 / 256, 256, 0, stream>>>(y3, y2d, stats_2, stats_1d, g2,
                                              b2, gd, bd, out);
}

// Round 13
// 237.837 us; speedup vs baseline: 1.0104x; 1.0104x over previous
//
#include <hip/hip_runtime.h>

// Problem constants (match reference setup_inputs)
constexpr int CN0 = 1000000;   // x rows
constexpr int CN1 = 300000;    // stem conv output rows
constexpr int CN2 = 80000;     // pooled rows
constexpr int CN3 = 30000;     // downsampled rows
constexpr float BN_EPS = 1e-5f;

typedef __attribute__((ext_vector_type(8))) short bf16x8;
typedef __attribute__((ext_vector_type(4))) float f32x4;

union FragU { uint4 u; bf16x8 b; };

__device__ __forceinline__ float2 bn_ab(float s, float q, float invn, float gamma, float beta) {
  float m = s * invn;
  float v = fmaf(q, invn, -m * m);
  float rstd = rsqrtf(v + BN_EPS);
  float a = gamma * rstd;
  float b = beta - m * a;
  return make_float2(a, b);
}

// round-to-nearest-even fp32 -> bf16
__device__ __forceinline__ unsigned short f2bf(float f) {
  unsigned u = __float_as_uint(f);
  u += 0x7FFFu + ((u >> 16) & 1u);
  return (unsigned short)(u >> 16);
}

// LDS-only barrier: waits ds ops, does NOT drain vmcnt -> prefetched global
// loads stay in flight across the barrier.
__device__ __forceinline__ void sync_lds() {
  asm volatile("s_waitcnt lgkmcnt(0)" ::: "memory");
  __builtin_amdgcn_s_barrier();
  asm volatile("" ::: "memory");
}

// ---------------------------------------------------------------------------
// Prep: x (f32 [1M][4]) -> xbf (bf16 [1M][4])
// ---------------------------------------------------------------------------
__global__ __launch_bounds__(256) void k_prep_x(
    const float* __restrict__ x, unsigned int* __restrict__ xbf) {
  int i = blockIdx.x * 256 + threadIdx.x;
  if (i >= CN0) return;
  float4 v = *(const float4*)(x + i * 4);
  uint2 p;
  p.x = (unsigned)f2bf(v.x) | ((unsigned)f2bf(v.y) << 16);
  p.y = (unsigned)f2bf(v.z) | ((unsigned)f2bf(v.w) << 16);
  *(uint2*)(xbf + i * 2) = p;
}

// ---------------------------------------------------------------------------
// Prep: W_stem [27][4][64] f32 -> per-lane MFMA B fragments:
// Wf[((ks*4+nf)*64 + lane)*8 + e] = W[k][d], k=ks*32+(lane>>4)*8+e (pad>=108),
// d = nf*16+(lane&15).
// ---------------------------------------------------------------------------
__global__ __launch_bounds__(256) void k_prep_stem(
    const float* __restrict__ W, unsigned short* __restrict__ Wt) {
  int f = blockIdx.x * 256 + threadIdx.x;  // 8192
  if (f >= 8192) return;
  int e = f & 7, lane = (f >> 3) & 63, nf = (f >> 9) & 3, ks = f >> 11;
  int k = ks * 32 + (lane >> 4) * 8 + e;
  int d = nf * 16 + (lane & 15);
  Wt[f] = (k < 108) ? f2bf(W[k * 64 + d]) : (unsigned short)0;
}

// ---------------------------------------------------------------------------
// Prep: dual weights [W1|Wd] -> per-lane fragment layout
// Wf[tap][ks1][nfg(0..7)][lane][e]: cin=ks1*32+(lane>>4)*8+e, d=nfg*16+(lane&15)
// ---------------------------------------------------------------------------
__global__ __launch_bounds__(256) void k_prep_dual(
    const float* __restrict__ W1, const float* __restrict__ Wd,
    unsigned short* __restrict__ Wf) {
  int f = blockIdx.x * 256 + threadIdx.x;  // 27*8192 = 221184
  if (f >= 27 * 8192) return;
  int tap = f >> 13, r = f & 8191;
  int ks1 = (r >> 12) & 1, nfg = (r >> 9) & 7, lane = (r >> 3) & 63, e = r & 7;
  int cin = ks1 * 32 + (lane >> 4) * 8 + e;
  int d = nfg * 16 + (lane & 15);
  float v = (d < 64) ? W1[(tap * 64 + cin) * 64 + d]
                     : Wd[(tap * 64 + cin) * 64 + (d - 64)];
  Wf[f] = f2bf(v);
}

__global__ __launch_bounds__(256) void k_prep_res(
    const float* __restrict__ W2, unsigned short* __restrict__ Wf) {
  int f = blockIdx.x * 256 + threadIdx.x;  // 27*4096 = 110592
  if (f >= 27 * 4096) return;
  int tap = f >> 12, r = f & 4095;
  int ks1 = (r >> 11) & 1, nfg = (r >> 9) & 3, lane = (r >> 3) & 63, e = r & 7;
  int cin = ks1 * 32 + (lane >> 4) * 8 + e;
  int d = nfg * 16 + (lane & 15);
  Wf[f] = f2bf(W2[(tap * 64 + cin) * 64 + d]);
}

// ---------------------------------------------------------------------------
// Stem conv via MFMA — r11/r6 T=4 version verbatim (measured 95 us; the
// 2-deep variant from r12 regressed: fabric-bound, not MLP-bound).
// ---------------------------------------------------------------------------
__global__ __launch_bounds__(256) void k_stem_mfma(
    const unsigned short* __restrict__ xbf, const int* __restrict__ neigh,
    const unsigned short* __restrict__ Wf, unsigned short* __restrict__ y1,
    float* __restrict__ stats) {
  constexpr int T = 4;  // tiles (of 64 nodes) per block; 1172 blocks
  __shared__ __align__(16) uint4 Bb[1024];  // 16 KB: B fragments, staged once
  const int tid = threadIdx.x;
  const int lane = tid & 63;
  const int wv = tid >> 6;
  const int l15 = lane & 15, lq = lane >> 4;
  const int g0 = blockIdx.x * T;

  // Stage B fragments (linear copy, conflict-free reads later)
  {
    const uint4* Wsrc = (const uint4*)Wf;
#pragma unroll
    for (int j = 0; j < 4; ++j) Bb[tid + j * 256] = Wsrc[tid + j * 256];
  }
  __syncthreads();  // nothing valuable in flight yet

  int idxA[8], idxB[8];
  FragU fragA[4], fragB[4];

#define LDIDX(g, dst)                                                   \
  {                                                                     \
    int node_ = (g)*64 + wv * 16 + l15;                                 \
    bool rowok_ = node_ < CN1;                                          \
    const int* nb_ = neigh + node_ * 27;                                \
    _Pragma("unroll") for (int ks_ = 0; ks_ < 4; ++ks_) {               \
      int tap0_ = ks_ * 8 + lq * 2;                                     \
      dst[ks_ * 2] = (rowok_ && tap0_ < 27) ? nb_[tap0_] : -1;          \
      dst[ks_ * 2 + 1] = (rowok_ && tap0_ + 1 < 27) ? nb_[tap0_ + 1] : -1; \
    }                                                                   \
  }

#define GATHER(idx, frag)                                               \
  {                                                                     \
    _Pragma("unroll") for (int ks_ = 0; ks_ < 4; ++ks_) {               \
      uint2 v0_ = {0u, 0u}, v1_ = {0u, 0u};                             \
      if (idx[ks_ * 2] >= 0)                                            \
        v0_ = *(const uint2*)(xbf + idx[ks_ * 2] * 4);                  \
      if (idx[ks_ * 2 + 1] >= 0)                                        \
        v1_ = *(const uint2*)(xbf + idx[ks_ * 2 + 1] * 4);              \
      frag[ks_].u.x = v0_.x; frag[ks_].u.y = v0_.y;                     \
      frag[ks_].u.z = v1_.x; frag[ks_].u.w = v1_.y;                     \
    }                                                                   \
  }

  // prologue: tile0 idx -> tile0 gathers -> tile1 idx
  LDIDX(0 + g0, idxA);
  GATHER(idxA, fragA);
  LDIDX(1 + g0, idxB);

  float sacc[4] = {0.f, 0.f, 0.f, 0.f};
  float qacc[4] = {0.f, 0.f, 0.f, 0.f};

#pragma unroll
  for (int t = 0; t < T; ++t) {
    FragU* cur = (t & 1) ? fragB : fragA;
    FragU* nxt = (t & 1) ? fragA : fragB;
    int* idn = (t & 1) ? idxA : idxB;    // idx of tile t+1 (already loaded)
    int* idn2 = (t & 1) ? idxB : idxA;   // slot for idx of tile t+2
    // issue next tile's gathers + idx loads (ride latency under compute)
    if (t + 1 < T) GATHER(idn, nxt);
    if (t + 2 < T) LDIDX(g0 + t + 2, idn2);

    // compute: 4 K-substeps x 4 col-fragments; B from LDS
    f32x4 acc[4] = {};
#pragma unroll
    for (int ks = 0; ks < 4; ++ks) {
#pragma unroll
      for (int nf = 0; nf < 4; ++nf) {
        bf16x8 b = *(const bf16x8*)&Bb[(ks * 4 + nf) * 64 + lane];
        acc[nf] = __builtin_amdgcn_mfma_f32_16x16x32_bf16(cur[ks].b, b,
                                                          acc[nf], 0, 0, 0);
      }
    }

    // epilogue: store + register stats. C/D: col=lane&15, row=(lane>>4)*4+r
    int n0 = (g0 + t) * 64 + wv * 16;
#pragma unroll
    for (int nf = 0; nf < 4; ++nf) {
      int c = nf * 16 + l15;
#pragma unroll
      for (int r = 0; r < 4; ++r) {
        int row = n0 + lq * 4 + r;
        float v = acc[nf][r];
        if (row < CN1) y1[row * 64 + c] = f2bf(v);
        sacc[nf] += v;
        qacc[nf] = fmaf(v, v, qacc[nf]);
      }
    }
  }
#undef LDIDX
#undef GATHER

  // cross-wave stats reduction (reuse Bb as scratch), one atomic set/block
  __syncthreads();
  float* S = (float*)Bb;  // [2][4 waves][64 cols]
#pragma unroll
  for (int nf = 0; nf < 4; ++nf) {
    float s = sacc[nf], q = qacc[nf];
    s += __shfl_xor(s, 16); s += __shfl_xor(s, 32);
    q += __shfl_xor(q, 16); q += __shfl_xor(q, 32);
    if (lane < 16) {
      S[wv * 64 + nf * 16 + lane] = s;
      S[256 + wv * 64 + nf * 16 + lane] = q;
    }
  }
  __syncthreads();
  if (tid < 64) {
    float s = S[tid] + S[64 + tid] + S[128 + tid] + S[192 + tid];
    float q = S[256 + tid] + S[320 + tid] + S[384 + tid] + S[448 + tid];
    atomicAdd(&stats[tid], s);
    atomicAdd(&stats[64 + tid], q);
  }
}

// ---------------------------------------------------------------------------
// Pool: h2[n][c] = relu(max_j BN(y1[child[n][j]][c])) on packed bf16 y1.
// ---------------------------------------------------------------------------
__global__ __launch_bounds__(256) void k_pool(
    const unsigned int* __restrict__ y1, const int* __restrict__ child,
    const float* __restrict__ stats, const float* __restrict__ gamma,
    const float* __restrict__ beta, unsigned int* __restrict__ h2) {
  const int tid = threadIdx.x;
  const int wd = tid & 31;
  const int n = blockIdx.x * 8 + (tid >> 5);
  const int c0 = wd * 2, c1 = c0 + 1;
  const int* crow = child + n * 8;
  int ch[8];
#pragma unroll
  for (int j = 0; j < 8; ++j) ch[j] = crow[j];
  unsigned vv[8];
#pragma unroll
  for (int j = 0; j < 8; ++j) vv[j] = y1[ch[j] * 32 + wd];

  float2 ab0 = bn_ab(stats[c0], stats[64 + c0], 1.0f / CN1, gamma[c0], beta[c0]);
  float2 ab1 = bn_ab(stats[c1], stats[64 + c1], 1.0f / CN1, gamma[c1], beta[c1]);
  float mx0 = -INFINITY, mn0 = INFINITY, mx1 = -INFINITY, mn1 = INFINITY;
#pragma unroll
  for (int j = 0; j < 8; ++j) {
    float v0 = __uint_as_float(vv[j] << 16);
    float v1 = __uint_as_float(vv[j] & 0xFFFF0000u);
    mx0 = fmaxf(mx0, v0); mn0 = fminf(mn0, v0);
    mx1 = fmaxf(mx1, v1); mn1 = fminf(mn1, v1);
  }
  float t0 = (ab0.x > 0.f) ? fmaf(ab0.x, mx0, ab0.y) : fmaf(ab0.x, mn0, ab0.y);
  float t1 = (ab1.x > 0.f) ? fmaf(ab1.x, mx1, ab1.y) : fmaf(ab1.x, mn1, ab1.y);
  unsigned o = (unsigned)f2bf(fmaxf(t0, 0.f)) |
               ((unsigned)f2bf(fmaxf(t1, 0.f)) << 16);
  h2[n * 32 + wd] = o;
}

// ---------------------------------------------------------------------------
// MFMA gathered conv, barrier-free / array-free, 32-node waves.
// A gathers 4 taps deep (4-slot rotation, +1 vs r12 — mconvs run at ~1.8
// waves/SIMD so they are gather-LATENCY bound); B 2-deep (qa/qb/qc, r12).
// All pipeline state = named scalars. FP order identical to r11/r12.
// ---------------------------------------------------------------------------
template <int OUTC>
__global__ __launch_bounds__(OUTC * 2) void k_mconv(
    const unsigned short* __restrict__ src, const int* __restrict__ neigh,
    const unsigned short* __restrict__ Wf, float* __restrict__ out,
    float* __restrict__ stats, int M) {
  constexpr int CG = OUTC / 64;      // col groups (2 or 1)
  constexpr int THREADS = OUTC * 2;  // 256 or 128
  constexpr int PT = CG * 512;       // uint4 per tap
  constexpr int K1 = 4 * CG;         // ks1=1 fragment offset (frags)
  __shared__ int nlds[64 * 27];

  const int tid = threadIdx.x;
  const int lane = tid & 63;
  const int w = tid >> 6;
  const int ng = w & 1, cg = w >> 1;   // cg==0 when OUTC==64
  const int l15 = lane & 15, lq = lane >> 4;
  const uint4* WfU = (const uint4*)Wf;
  const int cg4 = cg * 4;
  const int offA = (ng * 32 + l15) * 27;  // LDS idx offsets (literal +k reads)
  const int offB = offA + 16 * 27;

  // stage all 64 nodes' neighbor indices (coalesced)
  for (int e = tid; e < 64 * 27; e += THREADS) {
    int row = blockIdx.x * 64 + e / 27;
    nlds[e] = (row < M) ? neigh[row * 27 + e % 27] : -1;
  }

  FragU x0l, x0h, x1l, x1h, x2l, x2h, x3l, x3h;  // group A frags, 4-slot
  FragU y0l, y0h, y1l, y1h, y2l, y2h, y3l, y3h;  // group B frags
  FragU qa0, qa1, qa2, qa3, qa4, qa5, qa6, qa7;  // B 3-buf (2-deep)
  FragU qb0, qb1, qb2, qb3, qb4, qb5, qb6, qb7;
  FragU qc0, qc1, qc2, qc3, qc4, qc5, qc6, qc7;
  f32x4 ca0 = {0.f, 0.f, 0.f, 0.f}, ca1 = {0.f, 0.f, 0.f, 0.f};
  f32x4 ca2 = {0.f, 0.f, 0.f, 0.f}, ca3 = {0.f, 0.f, 0.f, 0.f};
  f32x4 cb0 = {0.f, 0.f, 0.f, 0.f}, cb1 = {0.f, 0.f, 0.f, 0.f};
  f32x4 cb2 = {0.f, 0.f, 0.f, 0.f}, cb3 = {0.f, 0.f, 0.f, 0.f};

#define LDB(QP, k)                                                         \
  {                                                                        \
    const uint4* bp_ = WfU + ((k)*PT + cg4 * 64 + lane);                   \
    (QP##0).u = bp_[0];                                                    \
    (QP##1).u = bp_[64];                                                   \
    (QP##2).u = bp_[128];                                                  \
    (QP##3).u = bp_[192];                                                  \
    (QP##4).u = bp_[K1 * 64];                                              \
    (QP##5).u = bp_[K1 * 64 + 64];                                         \
    (QP##6).u = bp_[K1 * 64 + 128];                                        \
    (QP##7).u = bp_[K1 * 64 + 192];                                        \
  }

#define GATH2(AL, AH, ix)                                                  \
  {                                                                        \
    int ix_ = (ix);                                                        \
    if (ix_ >= 0) {                                                        \
      const char* bp_ = (const char*)src + (size_t)ix_ * 128 + lq * 16;    \
      AL.u = *(const uint4*)bp_;                                           \
      AH.u = *(const uint4*)(bp_ + 64);                                    \
    } else {                                                               \
      AL.u = uint4{0u, 0u, 0u, 0u};                                        \
      AH.u = uint4{0u, 0u, 0u, 0u};                                        \
    }                                                                      \
  }

// per-acc order: (l, Qlow) then (h, Qhigh) — identical numerics to r11/r12;
// chains interleaved c0..c3 so dependent MFMAs are 4 apart.
#define MMG(AL, AH, C0, C1, C2, C3, QP)                                       \
  C0 = __builtin_amdgcn_mfma_f32_16x16x32_bf16((AL).b, (QP##0).b, C0, 0, 0, 0); \
  C1 = __builtin_amdgcn_mfma_f32_16x16x32_bf16((AL).b, (QP##1).b, C1, 0, 0, 0); \
  C2 = __builtin_amdgcn_mfma_f32_16x16x32_bf16((AL).b, (QP##2).b, C2, 0, 0, 0); \
  C3 = __builtin_amdgcn_mfma_f32_16x16x32_bf16((AL).b, (QP##3).b, C3, 0, 0, 0); \
  C0 = __builtin_amdgcn_mfma_f32_16x16x32_bf16((AH).b, (QP##4).b, C0, 0, 0, 0); \
  C1 = __builtin_amdgcn_mfma_f32_16x16x32_bf16((AH).b, (QP##5).b, C1, 0, 0, 0); \
  C2 = __builtin_amdgcn_mfma_f32_16x16x32_bf16((AH).b, (QP##6).b, C2, 0, 0, 0); \
  C3 = __builtin_amdgcn_mfma_f32_16x16x32_bf16((AH).b, (QP##7).b, C3, 0, 0, 0);

// TAP(k): prefetch B tap k+2 -> QN2; MFMA tap k (both groups, shared QP);
// gather tap k+4 into the slot just freed ((k+4)%4 == k%4).
#define TAP(k, XL, XH, YL, YH, QP, QN2)                \
  {                                                    \
    if ((k) + 2 < 27) LDB(QN2, (k) + 2)                \
    MMG(XL, XH, ca0, ca1, ca2, ca3, QP)                \
    MMG(YL, YH, cb0, cb1, cb2, cb3, QP)                \
    if ((k) + 4 < 27) {                                \
      GATH2(XL, XH, nlds[offA + (k) + 4])              \
      GATH2(YL, YH, nlds[offB + (k) + 4])              \
    }                                                  \
  }

  // B taps 0,1 issued before the barrier (ride across it)
  LDB(qa, 0)
  LDB(qb, 1)
  sync_lds();  // nlds visible

  // prologue gathers: taps 0..3, both groups (16 uint4 in flight)
  GATH2(x0l, x0h, nlds[offA + 0])
  GATH2(y0l, y0h, nlds[offB + 0])
  GATH2(x1l, x1h, nlds[offA + 1])
  GATH2(y1l, y1h, nlds[offB + 1])
  GATH2(x2l, x2h, nlds[offA + 2])
  GATH2(y2l, y2h, nlds[offB + 2])
  GATH2(x3l, x3h, nlds[offA + 3])
  GATH2(y3l, y3h, nlds[offB + 3])

  // slot = k%4, QP = q[k%3], QN2 = q[(k+2)%3]
  TAP(0,  x0l, x0h, y0l, y0h, qa, qc)
  TAP(1,  x1l, x1h, y1l, y1h, qb, qa)
  TAP(2,  x2l, x2h, y2l, y2h, qc, qb)
  TAP(3,  x3l, x3h, y3l, y3h, qa, qc)
  TAP(4,  x0l, x0h, y0l, y0h, qb, qa)
  TAP(5,  x1l, x1h, y1l, y1h, qc, qb)
  TAP(6,  x2l, x2h, y2l, y2h, qa, qc)
  TAP(7,  x3l, x3h, y3l, y3h, qb, qa)
  TAP(8,  x0l, x0h, y0l, y0h, qc, qb)
  TAP(9,  x1l, x1h, y1l, y1h, qa, qc)
  TAP(10, x2l, x2h, y2l, y2h, qb, qa)
  TAP(11, x3l, x3h, y3l, y3h, qc, qb)
  TAP(12, x0l, x0h, y0l, y0h, qa, qc)
  TAP(13, x1l, x1h, y1l, y1h, qb, qa)
  TAP(14, x2l, x2h, y2l, y2h, qc, qb)
  TAP(15, x3l, x3h, y3l, y3h, qa, qc)
  TAP(16, x0l, x0h, y0l, y0h, qb, qa)
  TAP(17, x1l, x1h, y1l, y1h, qc, qb)
  TAP(18, x2l, x2h, y2l, y2h, qa, qc)
  TAP(19, x3l, x3h, y3l, y3h, qb, qa)
  TAP(20, x0l, x0h, y0l, y0h, qc, qb)
  TAP(21, x1l, x1h, y1l, y1h, qa, qc)
  TAP(22, x2l, x2h, y2l, y2h, qb, qa)
  TAP(23, x3l, x3h, y3l, y3h, qc, qb)
  TAP(24, x0l, x0h, y0l, y0h, qa, qc)
  TAP(25, x1l, x1h, y1l, y1h, qb, qa)
  TAP(26, x2l, x2h, y2l, y2h, qc, qb)
#undef TAP
#undef MMG
#undef GATH2
#undef LDB

  // store (C/D: col=lane&15, row=(lane>>4)*4+r); group x rows, then +16
  const int rbA = blockIdx.x * 64 + ng * 32 + lq * 4;
#pragma unroll
  for (int nf = 0; nf < 4; ++nf) {
    f32x4 a = (nf == 0) ? ca0 : (nf == 1) ? ca1 : (nf == 2) ? ca2 : ca3;
    f32x4 b = (nf == 0) ? cb0 : (nf == 1) ? cb1 : (nf == 2) ? cb2 : cb3;
    int c = cg * 64 + nf * 16 + l15;
#pragma unroll
    for (int r = 0; r < 4; ++r) {
      int rowA = rbA + r, rowB = rbA + 16 + r;
      if (rowA < M) out[rowA * OUTC + c] = a[r];
      if (rowB < M) out[rowB * OUTC + c] = b[r];
    }
  }

  // stats (invalid rows contributed zeros); sum both groups
#pragma unroll
  for (int nf = 0; nf < 4; ++nf) {
    f32x4 a = (nf == 0) ? ca0 : (nf == 1) ? ca1 : (nf == 2) ? ca2 : ca3;
    f32x4 b = (nf == 0) ? cb0 : (nf == 1) ? cb1 : (nf == 2) ? cb2 : cb3;
    float s = 0.f, q = 0.f;
#pragma unroll
    for (int r = 0; r < 4; ++r) {
      s += a[r] + b[r];
      q += a[r] * a[r] + b[r] * b[r];
    }
    s += __shfl_xor(s, 16); s += __shfl_xor(s, 32);
    q += __shfl_xor(q, 16); q += __shfl_xor(q, 32);
    if (lane < 16) {
      int c = cg * 64 + nf * 16 + lane;
      atomicAdd(&stats[c], s);
      atomicAdd(&stats[OUTC + c], q);
    }
  }
}

// ---------------------------------------------------------------------------
// BN+ReLU on y2d channels 0..63 -> out1 (bf16)
// ---------------------------------------------------------------------------
__global__ __launch_bounds__(256) void k_bnrelu(
    const float* __restrict__ y2d, const float* __restrict__ stats,
    const float* __restrict__ gamma, const float* __restrict__ beta,
    unsigned short* __restrict__ out1) {
  int e = blockIdx.x * 256 + threadIdx.x;
  int i = e >> 6, c = e & 63;
  float2 ab = bn_ab(stats[c], stats[128 + c], 1.0f / CN3, gamma[c], beta[c]);
  out1[e] = f2bf(fmaxf(fmaf(ab.x, y2d[i * 128 + c], ab.y), 0.f));
}

// ---------------------------------------------------------------------------
// Final: relu(BN2(y3) + BNd(y2d[:,64:128]))
// ---------------------------------------------------------------------------
__global__ __launch_bounds__(256) void k_final(
    const float* __restrict__ y3, const float* __restrict__ y2d,
    const float* __restrict__ stats2, const float* __restrict__ stats1d,
    const float* __restrict__ g2, const float* __restrict__ b2,
    const float* __restrict__ gd, const float* __restrict__ bd,
    float* __restrict__ dout) {
  int e = blockIdx.x * 256 + threadIdx.x;
  int i = e >> 6, c = e & 63;
  float2 ab2 = bn_ab(stats2[c], stats2[64 + c], 1.0f / CN3, g2[c], b2[c]);
  float2 abd =
      bn_ab(stats1d[64 + c], stats1d[192 + c], 1.0f / CN3, gd[c], bd[c]);
  float o = fmaf(ab2.x, y3[e], ab2.y) + fmaf(abd.x, y2d[i * 128 + 64 + c], abd.y);
  dout[e] = fmaxf(o, 0.f);
}

// ---------------------------------------------------------------------------
extern "C" void kernel_launch(void* const* d_in, const int* in_sizes, int n_in,
                              void* d_out, int out_size, void* d_ws,
                              size_t ws_size, hipStream_t stream) {
  const float* x = (const float*)d_in[0];
  const int* neigh_stem = (const int*)d_in[1];
  const int* pool_child = (const int*)d_in[2];
  const int* neigh_ds = (const int*)d_in[3];
  const int* neigh_res = (const int*)d_in[4];
  const float* W_stem = (const float*)d_in[5];
  const float* g_stem = (const float*)d_in[6];
  const float* b_stem = (const float*)d_in[7];
  const float* W1 = (const float*)d_in[8];
  const float* g1 = (const float*)d_in[9];
  const float* b1 = (const float*)d_in[10];
  const float* W2 = (const float*)d_in[11];
  const float* g2 = (const float*)d_in[12];
  const float* b2 = (const float*)d_in[13];
  const float* Wd = (const float*)d_in[14];
  const float* gd = (const float*)d_in[15];
  const float* bd = (const float*)d_in[16];
  float* out = (float*)d_out;
  float* ws = (float*)d_ws;

  // Workspace layout (float units):
  unsigned short* y1bf = (unsigned short*)ws;              // N1*64 bf16 (9.6M f)
  float* y2d = ws;                                         // N3*128 f32 (reuse)
  unsigned short* out1bf = (unsigned short*)(ws + 3840000);// N3*64 bf16
  float* y3 = ws + 4800000;                                // N3*64 f32
  unsigned short* h2bf = (unsigned short*)(ws + 9600000);  // N2*64 bf16 (2.56M f)
  unsigned int* xbf = (unsigned int*)(ws + 12160000);      // N0*4 bf16 (2M f)
  unsigned short* Wst = (unsigned short*)(ws + 14160000);  // 8192 bf16
  unsigned short* Wdual = (unsigned short*)(ws + 14164096);// 221184 bf16
  unsigned short* Wres = (unsigned short*)(ws + 14274688); // 110592 bf16
  float* stats = ws + 14329984;                            // 512 f32
  float* stats_stem = stats;                               // [128]
  float* stats_1d = stats + 128;                           // [256]
  float* stats_2 = stats + 384;                            // [128]

  hipMemsetAsync(stats, 0, 512 * sizeof(float), stream);

  k_prep_x<<<(CN0 + 255) / 256, 256, 0, stream>>>(x, xbf);
  k_prep_stem<<<(8192 + 255) / 256, 256, 0, stream>>>(W_stem, Wst);
  k_prep_dual<<<(27 * 8192 + 255) / 256, 256, 0, stream>>>(W1, Wd, Wdual);
  k_prep_res<<<(27 * 4096 + 255) / 256, 256, 0, stream>>>(W2, Wres);

  // 4688 tiles of 64 nodes = 4 tiles x 1172 blocks
  k_stem_mfma<<<1172, 256, 0, stream>>>(
      (const unsigned short*)xbf, neigh_stem, Wst, y1bf, stats_stem);
  k_pool<<<CN2 / 8, 256, 0, stream>>>((const unsigned int*)y1bf, pool_child,
                                      stats_stem, g_stem, b_stem,
                                      (unsigned int*)h2bf);
  // 469 blocks of 64 nodes
  k_mconv<128><<<(CN3 + 63) / 64, 256, 0, stream>>>(h2bf, neigh_ds, Wdual,
                                                    y2d, stats_1d, CN3);
  k_bnrelu<<<CN3 * 64 / 256, 256, 0, stream>>>(y2d, stats_1d, g1, b1, out1bf);
  k_mconv<64><<<(CN3 + 63) / 64, 128, 0, stream>>>(out1bf, neigh_res, Wres,
                                                   y3, stats_2, CN3);
  k_final<<<CN3 * 64 / 256, 256, 0, stream>>>(y3, y2d, stats_2, stats_1d, g2,
                                              b2, gd, bd, out);
}